// Round 10
// baseline (131.080 us; speedup 1.0000x reference)
//
#include <hip/hip_runtime.h>
#include <hip/hip_bf16.h>

typedef short s16x8 __attribute__((ext_vector_type(8)));
typedef short s16x4 __attribute__((ext_vector_type(4)));
typedef float f32x4 __attribute__((ext_vector_type(4)));
typedef float f32x16 __attribute__((ext_vector_type(16)));
typedef unsigned int u32x4 __attribute__((ext_vector_type(4)));

#define S_LEN 2048
#define DMODEL 1024
#define NHEAD 16
#define HDIM 64
#define OUT_ELEMS 4194304   // B*S*D
#define HEAD_ELEMS 4194304  // B*H*S*HD
#define SCALE_LOG2 0.1803368801111204f  // 0.125 * log2(e), folded into Q

__device__ inline short f2bf(float f) {
  __hip_bfloat16 h = __float2bfloat16(f);  // RNE
  return __builtin_bit_cast(short, h);
}

__device__ inline f32x4 mfma16(s16x8 a, s16x8 b, f32x4 c) {
  return __builtin_amdgcn_mfma_f32_16x16x32_bf16(a, b, c, 0, 0, 0);
}
__device__ inline f32x16 mfma32(s16x8 a, s16x8 b, f32x16 c) {
  return __builtin_amdgcn_mfma_f32_32x32x16_bf16(a, b, c, 0, 0, 0);
}

typedef __attribute__((address_space(1))) const void gvoid;
typedef __attribute__((address_space(3))) void lvoid;
// async global->LDS, 16B/lane; LDS dest = wave-uniform base + lane*16
__device__ inline void gload_lds16(const void* g, void* l) {
  __builtin_amdgcn_global_load_lds((gvoid*)g, (lvoid*)l, 16, 0, 0);
}

// ---- elementwise f32 -> bf16 (8 elems/thread) ----
__global__ __launch_bounds__(256) void cvt_bf16(const float* __restrict__ in,
                                                short* __restrict__ out) {
  int g = blockIdx.x * 256 + threadIdx.x;
  const float* p = &in[(size_t)g * 8];
  f32x4 a = *(const f32x4*)p;
  f32x4 b = *(const f32x4*)(p + 4);
  s16x8 v;
#pragma unroll
  for (int j = 0; j < 4; j++) {
    v[j] = f2bf(a[j]);
    v[4 + j] = f2bf(b[j]);
  }
  *(s16x8*)&out[(size_t)g * 8] = v;
}

// ---- convert+transpose: in [R][C] f32 -> out [C][R] bf16 ----
__global__ __launch_bounds__(256) void transpose_cvt(
    const float* __restrict__ in, short* __restrict__ out, int R, int C) {
  int g = blockIdx.x * 256 + threadIdx.x;
  int c = g % C;
  int r0 = (g / C) * 8;
  s16x8 v;
#pragma unroll
  for (int j = 0; j < 8; j++) v[j] = f2bf(in[(size_t)(r0 + j) * C + c]);
  *(s16x8*)&out[(size_t)c * R + r0] = v;
}

// ---- GEMM: C = A[M,K] * Bt[N,K]^T + bias. bf16 in, global_load_lds staged.
// MODE 0: QKV scatter: Q(pre-scaled)->Ob0 bf16, K->Of f32 (+KwOut bf16),
//         V->Of f32 + VtOut bf16 transposed, sigma-permuted key order
// MODE 1: plain f32 row-major store to Of
template <int MODE>
__global__ __launch_bounds__(256) void gemm_bt(
    const short* __restrict__ A, const short* __restrict__ Bt,
    const float* __restrict__ bias, short* __restrict__ Ob0,
    float* __restrict__ Of, short* __restrict__ VtOut,
    short* __restrict__ KwOut, int M, int N, int K) {
  __shared__ short As[128 * 32];
  __shared__ short Bs[128 * 32];
  const int t = threadIdx.x;
  const int lane = t & 63;
  const int wid = t >> 6;
  const int wr = wid >> 1, wc = wid & 1;
  const int l16 = lane & 15, lg = lane >> 4;
  const int mbase = blockIdx.y * 128;
  const int nbase = blockIdx.x * 128;

  f32x4 acc[4][4];
#pragma unroll
  for (int m = 0; m < 4; m++)
#pragma unroll
    for (int n = 0; n < 4; n++) acc[m][n] = (f32x4){0.f, 0.f, 0.f, 0.f};

  // staging: wave wid stages rows [wid*32, wid*32+32); lane l -> row +l/4,
  // col (l&3)*8 shorts — matches HW lds dest = base + lane*16B
  const int srow = lane >> 2;
  const int scol = (lane & 3) * 8;
  const short* Ag = &A[(size_t)(mbase + wid * 32 + srow) * K + scol];
  const short* Bg = &Bt[(size_t)(nbase + wid * 32 + srow) * K + scol];
  short* AsW0 = &As[(wid * 32) * 32];
  short* AsW1 = &As[(wid * 32 + 16) * 32];
  short* BsW0 = &Bs[(wid * 32) * 32];
  short* BsW1 = &Bs[(wid * 32 + 16) * 32];

  for (int k0 = 0; k0 < K; k0 += 32) {
    __syncthreads();  // previous tile's reads complete before overwrite
    gload_lds16(Ag + k0, AsW0);
    gload_lds16(Ag + (size_t)16 * K + k0, AsW1);
    gload_lds16(Bg + k0, BsW0);
    gload_lds16(Bg + (size_t)16 * K + k0, BsW1);
    __syncthreads();  // drains vmcnt(0): tile resident
    s16x8 af[4], bfr[4];
#pragma unroll
    for (int m = 0; m < 4; m++)
      af[m] = *(const s16x8*)&As[(wr * 64 + m * 16 + l16) * 32 + lg * 8];
#pragma unroll
    for (int n = 0; n < 4; n++)
      bfr[n] = *(const s16x8*)&Bs[(wc * 64 + n * 16 + l16) * 32 + lg * 8];
#pragma unroll
    for (int m = 0; m < 4; m++)
#pragma unroll
      for (int n = 0; n < 4; n++)
        acc[m][n] = mfma16(af[m], bfr[n], acc[m][n]);
  }

#pragma unroll
  for (int m = 0; m < 4; m++) {
#pragma unroll
    for (int n = 0; n < 4; n++) {
      int gcol = nbase + wc * 64 + n * 16 + l16;
      float bv = bias[gcol];
      int part = gcol >> 10;
      int cin = gcol & 1023;
      int h = cin >> 6, hd = cin & 63;
      int grow0 = mbase + wr * 64 + m * 16 + lg * 4;
      float vr[4];
#pragma unroll
      for (int r = 0; r < 4; r++) vr[r] = acc[m][n][r] + bv;
      if (MODE == 0) {
        int bb = grow0 >> 11, s0 = grow0 & 2047;
        size_t base = ((size_t)(bb * NHEAD + h) * S_LEN + s0) * HDIM + hd;
        if (part == 0) {
#pragma unroll
          for (int r = 0; r < 4; r++)
            Ob0[base + (size_t)r * HDIM] = f2bf(vr[r] * SCALE_LOG2);
        } else if (part == 1) {
#pragma unroll
          for (int r = 0; r < 4; r++) Of[base + (size_t)r * HDIM] = vr[r];
          if (KwOut) {
#pragma unroll
            for (int r = 0; r < 4; r++)
              KwOut[base + (size_t)r * HDIM] = f2bf(vr[r]);
          }
        } else {
#pragma unroll
          for (int r = 0; r < 4; r++)
            Of[HEAD_ELEMS + base + (size_t)r * HDIM] = vr[r];
          s16x4 pk;
#pragma unroll
          for (int r = 0; r < 4; r++) pk[r] = f2bf(vr[r]);
          // sigma-permuted key position (runs of 4 preserved)
          int w32 = s0 & 31;
          int nw = ((w32 >> 4) << 4) | ((w32 & 4) << 1) | ((w32 & 8) >> 1);
          int sperm = (s0 & ~31) | nw;
          *(s16x4*)&VtOut[((size_t)(bb * NHEAD + h) * HDIM + hd) * S_LEN +
                          sperm] = pk;
        }
      } else {
#pragma unroll
        for (int r = 0; r < 4; r++) Of[(size_t)(grow0 + r) * N + gcol] = vr[r];
      }
    }
  }
}

// ==== attention: block = 128 q-rows (4 waves x 32q), KVBLK=64 shared ====
// K, Vt staged coalesced into XOR-swizzled LDS (double-buffered, T14 split).
__global__ __launch_bounds__(256, 2) void attn_fwd_kbf16(
    const short* __restrict__ Q, const short* __restrict__ K,
    const short* __restrict__ Vt, short* __restrict__ AO) {
  __shared__ short Ks[2][64][64];
  __shared__ short Vs[2][64][64];

  const int p = blockIdx.x;            // 512 blocks
  const int bh = p & 31;               // bh%8 pins XCD residue
  const int seg = (p >> 5) & 7;
  const int qi = (p < 256) ? (15 - seg) : seg;  // p,p+256 same CU: qi sums 15
  const int qb = qi * 128;
  const int nt = 2 * qi + 2;           // 64-key tiles

  const int tid = threadIdx.x;
  const int w = tid >> 6;
  const int lane = tid & 63;
  const int l32 = lane & 31;
  const int hi = lane >> 5;
  const int rsub = lane >> 3;          // 0..7
  const int sub = lane & 7;            // 16B chunk within 128B row

  const short* Qb = Q + (size_t)bh * (S_LEN * HDIM);
  const short* Kb = K + (size_t)bh * (S_LEN * HDIM);
  const short* Vb = Vt + (size_t)bh * (HDIM * S_LEN);
  const int b = bh >> 4, h = bh & 15;

  const int qrow = qb + 32 * w + l32;
  const int qminw = qb + 32 * w;
  const int qmaxw = qminw + 31;

  s16x8 qf[4];
#pragma unroll
  for (int c = 0; c < 4; c++)
    qf[c] = *(const s16x8*)&Qb[(size_t)qrow * HDIM + c * 16 + hi * 8];

  f32x16 acc0 = {0.f}, acc1 = {0.f};
  float m = -1e30f, ll = 0.f;

  s16x8 kreg[2], vreg[2];
  auto LOADT = [&](int kt) {
    const int kb = kt * 64;
#pragma unroll
    for (int c = 0; c < 2; c++) {
      int row = 16 * w + 8 * c + rsub;
      int gs = sub ^ (row & 7);  // inverse swizzle on global source
      kreg[c] = *(const s16x8*)&Kb[(size_t)(kb + row) * HDIM + gs * 8];
      vreg[c] = *(const s16x8*)&Vb[(size_t)row * S_LEN + kb + gs * 8];
    }
  };
  auto WRITET = [&](int bb) {
#pragma unroll
    for (int c = 0; c < 2; c++) {
      int row = 16 * w + 8 * c + rsub;
      *(s16x8*)&Ks[bb][row][sub * 8] = kreg[c];
      *(s16x8*)&Vs[bb][row][sub * 8] = vreg[c];
    }
  };

  LOADT(0);
  WRITET(0);
  __syncthreads();
  int cur = 0;

#pragma unroll 1
  for (int kt = 0; kt < nt; kt++) {
    const int kb = kt * 64;
    if (kt + 1 < nt) LOADT(kt + 1);
    if (kb <= qmaxw) {
      f32x16 S0 = {0.f}, S1 = {0.f};
#pragma unroll
      for (int c = 0; c < 4; c++) {
        int cs = c * 2 + hi;
        int r0 = l32;
        int r1 = 32 + l32;
        s16x8 k0 = *(const s16x8*)&Ks[cur][r0][(cs ^ (r0 & 7)) * 8];
        s16x8 k1 = *(const s16x8*)&Ks[cur][r1][(cs ^ (r1 & 7)) * 8];
        S0 = mfma32(k0, qf[c], S0);
        S1 = mfma32(k1, qf[c], S1);
      }
      if (kb + 63 > qminw) {
#pragma unroll
        for (int r = 0; r < 16; r++) {
          int key0 = kb + (r & 3) + 8 * (r >> 2) + 4 * hi;
          S0[r] = (key0 <= qrow) ? S0[r] : -1e30f;
          S1[r] = (key0 + 32 <= qrow) ? S1[r] : -1e30f;
        }
      }
      float t8[8];
#pragma unroll
      for (int r = 0; r < 8; r++)
        t8[r] = fmaxf(fmaxf(S0[2 * r], S0[2 * r + 1]),
                      fmaxf(S1[2 * r], S1[2 * r + 1]));
      float tmax = fmaxf(fmaxf(fmaxf(t8[0], t8[1]), fmaxf(t8[2], t8[3])),
                         fmaxf(fmaxf(t8[4], t8[5]), fmaxf(t8[6], t8[7])));
      tmax = fmaxf(tmax, __shfl_xor(tmax, 32));
      if (!__all(tmax <= m + 11.0f)) {
        float mn = fmaxf(m, tmax);
        float alpha = __builtin_amdgcn_exp2f(m - mn);
        ll *= alpha;
#pragma unroll
        for (int r = 0; r < 16; r++) {
          acc0[r] *= alpha;
          acc1[r] *= alpha;
        }
        m = mn;
      }
#pragma unroll
      for (int r = 0; r < 16; r++) {
        S0[r] = __builtin_amdgcn_exp2f(S0[r] - m);
        S1[r] = __builtin_amdgcn_exp2f(S1[r] - m);
      }
      float s8[8];
#pragma unroll
      for (int r = 0; r < 8; r++)
        s8[r] = (S0[2 * r] + S0[2 * r + 1]) + (S1[2 * r] + S1[2 * r + 1]);
      float rs = ((s8[0] + s8[1]) + (s8[2] + s8[3])) +
                 ((s8[4] + s8[5]) + (s8[6] + s8[7]));
      rs += __shfl_xor(rs, 32);
      ll += rs;
#pragma unroll
      for (int half = 0; half < 2; half++) {
        const f32x16& S = half ? S1 : S0;
        u32x4 pbAv, pbBv;
#pragma unroll
        for (int g = 0; g < 4; g++) {
          unsigned int lo = (unsigned short)f2bf(S[2 * g]);
          unsigned int h16 = (unsigned short)f2bf(S[2 * g + 1]);
          pbAv[g] = lo | (h16 << 16);
          unsigned int lo2 = (unsigned short)f2bf(S[8 + 2 * g]);
          unsigned int h162 = (unsigned short)f2bf(S[9 + 2 * g]);
          pbBv[g] = lo2 | (h162 << 16);
        }
#pragma unroll
        for (int gg = 0; gg < 2; gg++) {
          s16x8 pb = __builtin_bit_cast(s16x8, gg ? pbBv : pbAv);
          int cs = (half * 2 + gg) * 2 + hi;
          int v0r = l32;
          int v1r = 32 + l32;
          s16x8 va0 = *(const s16x8*)&Vs[cur][v0r][(cs ^ (v0r & 7)) * 8];
          s16x8 va1 = *(const s16x8*)&Vs[cur][v1r][(cs ^ (v1r & 7)) * 8];
          acc0 = mfma32(va0, pb, acc0);
          acc1 = mfma32(va1, pb, acc1);
        }
      }
    }
    if (kt + 1 < nt) WRITET(cur ^ 1);
    __syncthreads();
    cur ^= 1;
  }

  float inv = 1.f / ll;
  size_t rowbase = ((size_t)(b * S_LEN + qrow)) * DMODEL + h * HDIM;
#pragma unroll
  for (int g = 0; g < 4; g++) {
    s16x4 o0, o1;
#pragma unroll
    for (int u = 0; u < 4; u++) {
      o0[u] = f2bf(acc0[4 * g + u] * inv);
      o1[u] = f2bf(acc1[4 * g + u] * inv);
    }
    *(s16x4*)&AO[rowbase + 8 * g + 4 * hi] = o0;
    *(s16x4*)&AO[rowbase + 32 + 8 * g + 4 * hi] = o1;
  }
}

// ---- fallback (ws too small): k-split kernel, f32 K ----
__global__ __launch_bounds__(256, 4) void attn_fwd_kf32(
    const short* __restrict__ Q, const float* __restrict__ Kraw,
    const short* __restrict__ Vt, short* __restrict__ AO) {
  __shared__ float XFER[2][64][37];
  const int p = blockIdx.x;
  const int xcd = p & 7;
  const int rank = p >> 3;
  const int bh = (xcd << 2) | (rank >> 5);
  const int pr = rank & 31;
  const int tid = threadIdx.x;
  const int w = tid >> 6;
  const int lane = tid & 63;
  const int l32 = lane & 31;
  const int hi = lane >> 5;
  const short* Qb = Q + (size_t)bh * (S_LEN * HDIM);
  const short* Vb = Vt + (size_t)bh * (HDIM * S_LEN);
  const float* Kb32 = Kraw + (size_t)bh * (S_LEN * HDIM);
  const int b = bh >> 4, h = bh & 15;

#pragma unroll 1
  for (int ph = 0; ph < 2; ph++) {
    const int j = ph ? pr : 63 - pr;
    const int qb = j * 32;
    s16x8 qf[4];
#pragma unroll
    for (int c = 0; c < 4; c++)
      qf[c] = *(const s16x8*)&Qb[(size_t)(qb + l32) * HDIM + c * 16 + hi * 8];
    f32x16 acc0 = {0.f}, acc1 = {0.f};
    float m = -1e30f, ll = 0.f;
#pragma unroll 1
    for (int kt = w; kt <= j; kt += 4) {
      const int kb = kt * 32;
      f32x16 S = {0.f};
#pragma unroll
      for (int c = 0; c < 4; c++) {
        const float* kr = &Kb32[(size_t)(kb + l32) * HDIM + c * 16 + hi * 8];
        f32x4 k0 = *(const f32x4*)kr, k1 = *(const f32x4*)(kr + 4);
        s16x8 kf;
#pragma unroll
        for (int u = 0; u < 4; u++) {
          kf[u] = f2bf(k0[u]);
          kf[4 + u] = f2bf(k1[u]);
        }
        S = mfma32(kf, qf[c], S);
      }
      const short* vr0 = &Vb[(size_t)l32 * S_LEN + kb + hi * 8];
      const short* vr1 = &Vb[(size_t)(32 + l32) * S_LEN + kb + hi * 8];
      s16x8 va00 = *(const s16x8*)vr0;
      s16x8 va01 = *(const s16x8*)(vr0 + 16);
      s16x8 va10 = *(const s16x8*)vr1;
      s16x8 va11 = *(const s16x8*)(vr1 + 16);
      if (kt == j) {
#pragma unroll
        for (int r = 0; r < 16; r++) {
          int keyl = (r & 3) + 8 * (r >> 2) + 4 * hi;
          S[r] = (keyl <= l32) ? S[r] : -1e30f;
        }
      }
      float t8[8];
#pragma unroll
      for (int r = 0; r < 8; r++) t8[r] = fmaxf(S[2 * r], S[2 * r + 1]);
      float tmax = fmaxf(fmaxf(fmaxf(t8[0], t8[1]), fmaxf(t8[2], t8[3])),
                         fmaxf(fmaxf(t8[4], t8[5]), fmaxf(t8[6], t8[7])));
      tmax = fmaxf(tmax, __shfl_xor(tmax, 32));
      if (!__all(tmax <= m + 11.0f)) {
        float mn = fmaxf(m, tmax);
        float alpha = __builtin_amdgcn_exp2f(m - mn);
        ll *= alpha;
#pragma unroll
        for (int r = 0; r < 16; r++) {
          acc0[r] *= alpha;
          acc1[r] *= alpha;
        }
        m = mn;
      }
#pragma unroll
      for (int r = 0; r < 16; r++) S[r] = __builtin_amdgcn_exp2f(S[r] - m);
      float s8[8];
#pragma unroll
      for (int r = 0; r < 8; r++) s8[r] = S[2 * r] + S[2 * r + 1];
      float rs = ((s8[0] + s8[1]) + (s8[2] + s8[3])) +
                 ((s8[4] + s8[5]) + (s8[6] + s8[7]));
      rs += __shfl_xor(rs, 32);
      ll += rs;
      u32x4 pb0v, pb1v;
#pragma unroll
      for (int g = 0; g < 4; g++) {
        unsigned int lo = (unsigned short)f2bf(S[2 * g]);
        unsigned int h16 = (unsigned short)f2bf(S[2 * g + 1]);
        pb0v[g] = lo | (h16 << 16);
        unsigned int lo2 = (unsigned short)f2bf(S[8 + 2 * g]);
        unsigned int h162 = (unsigned short)f2bf(S[9 + 2 * g]);
        pb1v[g] = lo2 | (h162 << 16);
      }
      s16x8 pb0 = __builtin_bit_cast(s16x8, pb0v);
      s16x8 pb1 = __builtin_bit_cast(s16x8, pb1v);
      acc0 = mfma32(va00, pb0, acc0);
      acc1 = mfma32(va10, pb0, acc1);
      acc0 = mfma32(va01, pb1, acc0);
      acc1 = mfma32(va11, pb1, acc1);
    }
    if (w & 1) {
      float* dst = &XFER[w >> 1][lane][0];
      dst[0] = m; dst[1] = ll;
#pragma unroll
      for (int r = 0; r < 16; r++) { dst[2 + r] = acc0[r]; dst[18 + r] = acc1[r]; }
    }
    __syncthreads();
    if (!(w & 1)) {
      const float* src = &XFER[w >> 1][lane][0];
      float m2 = src[0], l2 = src[1];
      float M = fmaxf(m, m2);
      float a1 = __builtin_amdgcn_exp2f(m - M);
      float a2 = __builtin_amdgcn_exp2f(m2 - M);
      ll = ll * a1 + l2 * a2;
#pragma unroll
      for (int r = 0; r < 16; r++) {
        acc0[r] = acc0[r] * a1 + src[2 + r] * a2;
        acc1[r] = acc1[r] * a1 + src[18 + r] * a2;
      }
      m = M;
    }
    __syncthreads();
    if (w == 2) {
      float* dst = &XFER[0][lane][0];
      dst[0] = m; dst[1] = ll;
#pragma unroll
      for (int r = 0; r < 16; r++) { dst[2 + r] = acc0[r]; dst[18 + r] = acc1[r]; }
    }
    __syncthreads();
    if (w == 0) {
      const float* src = &XFER[0][lane][0];
      float m2 = src[0], l2 = src[1];
      float M = fmaxf(m, m2);
      float a1 = __builtin_amdgcn_exp2f(m - M);
      float a2 = __builtin_amdgcn_exp2f(m2 - M);
      ll = ll * a1 + l2 * a2;
#pragma unroll
      for (int r = 0; r < 16; r++) {
        acc0[r] = acc0[r] * a1 + src[2 + r] * a2;
        acc1[r] = acc1[r] * a1 + src[18 + r] * a2;
      }
      float inv = 1.f / ll;
      size_t rowbase = ((size_t)(b * S_LEN + qb + l32)) * DMODEL + h * HDIM;
#pragma unroll
      for (int g = 0; g < 4; g++) {
        s16x4 o0, o1;
#pragma unroll
        for (int u = 0; u < 4; u++) {
          o0[u] = f2bf(acc0[4 * g + u] * inv);
          o1[u] = f2bf(acc1[4 * g + u] * inv);
        }
        *(s16x4*)&AO[rowbase + 8 * g + 4 * hi] = o0;
        *(s16x4*)&AO[rowbase + 32 + 8 * g + 4 * hi] = o1;
      }
    }
    __syncthreads();
  }
}

extern "C" void kernel_launch(void* const* d_in, const int* in_sizes, int n_in,
                              void* d_out, int out_size, void* d_ws,
                              size_t ws_size, hipStream_t stream) {
  const float* x = (const float*)d_in[0];
  const float* w_qkv = (const float*)d_in[1];
  const float* b_qkv = (const float*)d_in[2];
  const float* w_proj = (const float*)d_in[3];
  const float* b_proj = (const float*)d_in[4];
  float* out = (float*)d_out;
  float* presentK = out + OUT_ELEMS;  // f32 [bh][S][64]

  // bf16 copy of x lives in the (dead until proj) `out` region: 8MB of 16MB
  short* xbf = (short*)out;

  short* ws = (short*)d_ws;
  const bool kbf16 = ws_size >= (size_t)35651584;  // 17,825,792 shorts

  short *Qw, *Vt, *wprojT, *wqkvT, *attnout, *Kw;
  if (kbf16) {
    Qw = ws;                  // 4,194,304
    Kw = ws + 4194304;        // 4,194,304
    Vt = ws + 8388608;        // 4,194,304
    wprojT = ws + 12582912;   // 1,048,576
    wqkvT = ws + 13631488;    // 3,145,728 (dead after QKV gemm)
    attnout = ws + 13631488;  // 4,194,304 (overlays wqkvT)
  } else {
    if (ws_size < (size_t)27262976) return;
    Qw = ws;
    Vt = ws + 4194304;
    wprojT = ws + 8388608;
    wqkvT = ws + 9437184;
    attnout = ws + 9437184;
    Kw = nullptr;
  }

  // x f32 -> bf16 (2048 blocks x 256 thr x 8 elems = 4M elems)
  cvt_bf16<<<dim3(2048), 256, 0, stream>>>(x, xbf);
  transpose_cvt<<<dim3(1536), 256, 0, stream>>>(w_qkv, wqkvT, 1024, 3072);
  transpose_cvt<<<dim3(512), 256, 0, stream>>>(w_proj, wprojT, 1024, 1024);
  // QKV projection: Q(pre-scaled)->Qw, K->presentK f32 (+Kw bf16), V->f32+Vt
  gemm_bt<0><<<dim3(24, 32), 256, 0, stream>>>(
      xbf, wqkvT, b_qkv, Qw, presentK, Vt, Kw, 4096, 3072, 1024);
  // causal attention
  if (kbf16)
    attn_fwd_kbf16<<<dim3(512), 256, 0, stream>>>(Qw, Kw, Vt, attnout);
  else
    attn_fwd_kf32<<<dim3(1024), 256, 0, stream>>>(Qw, presentK, Vt, attnout);
  // output projection -> f32 out (overwrites xbf region; xbf dead by now)
  gemm_bt<1><<<dim3(8, 32), 256, 0, stream>>>(
      attnout, wprojT, b_proj, nullptr, out, nullptr, nullptr, 4096, 1024,
      1024);
}

// Round 11
// 127.435 us; speedup vs baseline: 1.0286x; 1.0286x over previous
//
#include <hip/hip_runtime.h>
#include <hip/hip_bf16.h>

typedef short s16x8 __attribute__((ext_vector_type(8)));
typedef short s16x4 __attribute__((ext_vector_type(4)));
typedef float f32x4 __attribute__((ext_vector_type(4)));
typedef float f32x16 __attribute__((ext_vector_type(16)));
typedef unsigned int u32x4 __attribute__((ext_vector_type(4)));

#define S_LEN 2048
#define DMODEL 1024
#define NHEAD 16
#define HDIM 64
#define OUT_ELEMS 4194304   // B*S*D
#define HEAD_ELEMS 4194304  // B*H*S*HD
#define SCALE_LOG2 0.1803368801111204f  // 0.125 * log2(e), folded into Q

__device__ inline short f2bf(float f) {
  __hip_bfloat16 h = __float2bfloat16(f);  // RNE
  return __builtin_bit_cast(short, h);
}

__device__ inline f32x4 mfma16(s16x8 a, s16x8 b, f32x4 c) {
  return __builtin_amdgcn_mfma_f32_16x16x32_bf16(a, b, c, 0, 0, 0);
}
__device__ inline f32x16 mfma32(s16x8 a, s16x8 b, f32x16 c) {
  return __builtin_amdgcn_mfma_f32_32x32x16_bf16(a, b, c, 0, 0, 0);
}

typedef __attribute__((address_space(1))) const void gvoid;
typedef __attribute__((address_space(3))) void lvoid;
// async global->LDS, 16B/lane; LDS dest = wave-uniform base + lane*16
__device__ inline void gload_lds16(const void* g, void* l) {
  __builtin_amdgcn_global_load_lds((gvoid*)g, (lvoid*)l, 16, 0, 0);
}

// ---- elementwise f32 -> bf16 (8 elems/thread) ----
__global__ __launch_bounds__(256) void cvt_bf16(const float* __restrict__ in,
                                                short* __restrict__ out) {
  int g = blockIdx.x * 256 + threadIdx.x;
  const float* p = &in[(size_t)g * 8];
  f32x4 a = *(const f32x4*)p;
  f32x4 b = *(const f32x4*)(p + 4);
  s16x8 v;
#pragma unroll
  for (int j = 0; j < 4; j++) {
    v[j] = f2bf(a[j]);
    v[4 + j] = f2bf(b[j]);
  }
  *(s16x8*)&out[(size_t)g * 8] = v;
}

// ---- convert+transpose: in [R][C] f32 -> out [C][R] bf16 (weights) ----
__global__ __launch_bounds__(256) void transpose_cvt(
    const float* __restrict__ in, short* __restrict__ out, int R, int C) {
  int g = blockIdx.x * 256 + threadIdx.x;
  int c = g % C;
  int r0 = (g / C) * 8;
  s16x8 v;
#pragma unroll
  for (int j = 0; j < 8; j++) v[j] = f2bf(in[(size_t)(r0 + j) * C + c]);
  *(s16x8*)&out[(size_t)c * R + r0] = v;
}

// ---- presentV f32 [bh][S][64] -> Vt bf16 [bh][64][S] with sigma key perm --
// LDS-tiled: coalesced reads AND writes. sigma = swap bits 2,3 of key index.
__global__ __launch_bounds__(256) void vtrans(const float* __restrict__ Vf,
                                              short* __restrict__ Vt) {
  __shared__ short Vl[64][70];
  const int p = blockIdx.x;  // 1024 = 32 ktile x 32 bh
  const int bh = p & 31;
  const int kt = p >> 5;
  const float* src = Vf + ((size_t)bh * S_LEN + (size_t)kt * 64) * HDIM;
  short* dst = Vt + (size_t)bh * (HDIM * S_LEN) + kt * 64;
  const int t = threadIdx.x;
  {
    int row = t >> 2, col = (t & 3) * 16;
    const float* s = &src[row * 64 + col];
    f32x4 a0 = *(const f32x4*)s;
    f32x4 a1 = *(const f32x4*)(s + 4);
    f32x4 a2 = *(const f32x4*)(s + 8);
    f32x4 a3 = *(const f32x4*)(s + 12);
    s16x8 v0, v1;
#pragma unroll
    for (int j = 0; j < 4; j++) {
      v0[j] = f2bf(a0[j]); v0[4 + j] = f2bf(a1[j]);
      v1[j] = f2bf(a2[j]); v1[4 + j] = f2bf(a3[j]);
    }
    *(s16x8*)&Vl[row][col] = v0;
    *(s16x8*)&Vl[row][col + 8] = v1;
  }
  __syncthreads();
  {
    int hd = t >> 2, kg = (t & 3) * 16;
    const int perm4[4] = {0, 2, 1, 3};  // swap bits 0,1 of run index
    s16x8 o0, o1;
#pragma unroll
    for (int pp = 0; pp < 8; pp++)
      o0[pp] = Vl[kg + (pp & 3) + perm4[pp >> 2] * 4][hd];
#pragma unroll
    for (int pp = 0; pp < 8; pp++)
      o1[pp] = Vl[kg + ((pp + 8) & 3) + perm4[(pp + 8) >> 2] * 4][hd];
    *(s16x8*)&dst[(size_t)hd * S_LEN + kg] = o0;
    *(s16x8*)&dst[(size_t)hd * S_LEN + kg + 8] = o1;
  }
}

// ---- GEMM: C = A[M,K] * Bt[N,K]^T + bias. bf16, gload_lds, BK=64, swizzle.
// LDS[row][g] holds global granule g^(row&7) (16B granules, 8 per 128B row).
// MODE 0: QKV scatter: Q(pre-scaled)->Ob0 bf16, K->Of f32 + KwOut bf16,
//         V->Of f32.   MODE 1: plain f32 row-major store to Of.
template <int MODE>
__global__ __launch_bounds__(256) void gemm_bt(
    const short* __restrict__ A, const short* __restrict__ Bt,
    const float* __restrict__ bias, short* __restrict__ Ob0,
    float* __restrict__ Of, short* __restrict__ KwOut, int M, int N, int K) {
  __shared__ short As[128 * 64];
  __shared__ short Bs[128 * 64];
  const int t = threadIdx.x;
  const int lane = t & 63;
  const int wid = t >> 6;
  const int wr = wid >> 1, wc = wid & 1;
  const int l16 = lane & 15, lg = lane >> 4;
  const int mbase = blockIdx.y * 128;
  const int nbase = blockIdx.x * 128;

  f32x4 acc[4][4];
#pragma unroll
  for (int m = 0; m < 4; m++)
#pragma unroll
    for (int n = 0; n < 4; n++) acc[m][n] = (f32x4){0.f, 0.f, 0.f, 0.f};

  // staging: per gload, 64 lanes x 16B = 8 rows x 128B. Wave stages 32 rows.
  const int srow = lane >> 3;                 // 0..7 (= row & 7)
  const int sgr = (lane & 7) ^ srow;          // inverse-swizzled src granule
  const short* Ag = &A[(size_t)(mbase + wid * 32 + srow) * K + sgr * 8];
  const short* Bg = &Bt[(size_t)(nbase + wid * 32 + srow) * K + sgr * 8];

  for (int k0 = 0; k0 < K; k0 += 64) {
    __syncthreads();  // previous tile's reads complete before overwrite
#pragma unroll
    for (int c = 0; c < 4; c++)
      gload_lds16(Ag + (size_t)(c * 8) * K + k0, &As[(wid * 32 + c * 8) * 64]);
#pragma unroll
    for (int c = 0; c < 4; c++)
      gload_lds16(Bg + (size_t)(c * 8) * K + k0, &Bs[(wid * 32 + c * 8) * 64]);
    __syncthreads();  // drains vmcnt: tile resident
    s16x8 af[4][2], bfr[4][2];
#pragma unroll
    for (int m = 0; m < 4; m++) {
      int row = wr * 64 + m * 16 + l16;
#pragma unroll
      for (int h = 0; h < 2; h++) {
        int gr = (h * 4 + lg) ^ (row & 7);
        af[m][h] = *(const s16x8*)&As[row * 64 + gr * 8];
      }
    }
#pragma unroll
    for (int n = 0; n < 4; n++) {
      int row = wc * 64 + n * 16 + l16;
#pragma unroll
      for (int h = 0; h < 2; h++) {
        int gr = (h * 4 + lg) ^ (row & 7);
        bfr[n][h] = *(const s16x8*)&Bs[row * 64 + gr * 8];
      }
    }
#pragma unroll
    for (int m = 0; m < 4; m++)
#pragma unroll
      for (int n = 0; n < 4; n++) {
        acc[m][n] = mfma16(af[m][0], bfr[n][0], acc[m][n]);
        acc[m][n] = mfma16(af[m][1], bfr[n][1], acc[m][n]);
      }
  }

#pragma unroll
  for (int m = 0; m < 4; m++) {
#pragma unroll
    for (int n = 0; n < 4; n++) {
      int gcol = nbase + wc * 64 + n * 16 + l16;
      float bv = bias[gcol];
      int part = gcol >> 10;
      int cin = gcol & 1023;
      int h = cin >> 6, hd = cin & 63;
      int grow0 = mbase + wr * 64 + m * 16 + lg * 4;
      float vr[4];
#pragma unroll
      for (int r = 0; r < 4; r++) vr[r] = acc[m][n][r] + bv;
      if (MODE == 0) {
        int bb = grow0 >> 11, s0 = grow0 & 2047;
        size_t base = ((size_t)(bb * NHEAD + h) * S_LEN + s0) * HDIM + hd;
        if (part == 0) {
#pragma unroll
          for (int r = 0; r < 4; r++)
            Ob0[base + (size_t)r * HDIM] = f2bf(vr[r] * SCALE_LOG2);
        } else if (part == 1) {
#pragma unroll
          for (int r = 0; r < 4; r++) Of[base + (size_t)r * HDIM] = vr[r];
#pragma unroll
          for (int r = 0; r < 4; r++)
            KwOut[base + (size_t)r * HDIM] = f2bf(vr[r]);
        } else {
#pragma unroll
          for (int r = 0; r < 4; r++)
            Of[HEAD_ELEMS + base + (size_t)r * HDIM] = vr[r];
        }
      } else {
#pragma unroll
        for (int r = 0; r < 4; r++) Of[(size_t)(grow0 + r) * N + gcol] = vr[r];
      }
    }
  }
}

// ==== attention: block = 128 q-rows (4 waves x 32q), KVBLK=64 shared ====
__global__ __launch_bounds__(256, 2) void attn_fwd_kbf16(
    const short* __restrict__ Q, const short* __restrict__ K,
    const short* __restrict__ Vt, short* __restrict__ AO) {
  __shared__ short Ks[2][64][64];
  __shared__ short Vs[2][64][64];

  const int p = blockIdx.x;            // 512 blocks
  const int bh = p & 31;
  const int seg = (p >> 5) & 7;
  const int qi = (p < 256) ? (15 - seg) : seg;
  const int qb = qi * 128;
  const int nt = 2 * qi + 2;

  const int tid = threadIdx.x;
  const int w = tid >> 6;
  const int lane = tid & 63;
  const int l32 = lane & 31;
  const int hi = lane >> 5;
  const int rsub = lane >> 3;
  const int sub = lane & 7;

  const short* Qb = Q + (size_t)bh * (S_LEN * HDIM);
  const short* Kb = K + (size_t)bh * (S_LEN * HDIM);
  const short* Vb = Vt + (size_t)bh * (HDIM * S_LEN);
  const int b = bh >> 4, h = bh & 15;

  const int qrow = qb + 32 * w + l32;
  const int qminw = qb + 32 * w;
  const int qmaxw = qminw + 31;

  s16x8 qf[4];
#pragma unroll
  for (int c = 0; c < 4; c++)
    qf[c] = *(const s16x8*)&Qb[(size_t)qrow * HDIM + c * 16 + hi * 8];

  f32x16 acc0 = {0.f}, acc1 = {0.f};
  float m = -1e30f, ll = 0.f;

  s16x8 kreg[2], vreg[2];
  auto LOADT = [&](int kt) {
    const int kb = kt * 64;
#pragma unroll
    for (int c = 0; c < 2; c++) {
      int row = 16 * w + 8 * c + rsub;
      int gs = sub ^ (row & 7);
      kreg[c] = *(const s16x8*)&Kb[(size_t)(kb + row) * HDIM + gs * 8];
      vreg[c] = *(const s16x8*)&Vb[(size_t)row * S_LEN + kb + gs * 8];
    }
  };
  auto WRITET = [&](int bb) {
#pragma unroll
    for (int c = 0; c < 2; c++) {
      int row = 16 * w + 8 * c + rsub;
      *(s16x8*)&Ks[bb][row][sub * 8] = kreg[c];
      *(s16x8*)&Vs[bb][row][sub * 8] = vreg[c];
    }
  };

  LOADT(0);
  WRITET(0);
  __syncthreads();
  int cur = 0;

#pragma unroll 1
  for (int kt = 0; kt < nt; kt++) {
    const int kb = kt * 64;
    if (kt + 1 < nt) LOADT(kt + 1);
    if (kb <= qmaxw) {
      f32x16 S0 = {0.f}, S1 = {0.f};
#pragma unroll
      for (int c = 0; c < 4; c++) {
        int cs = c * 2 + hi;
        int r0 = l32;
        int r1 = 32 + l32;
        s16x8 k0 = *(const s16x8*)&Ks[cur][r0][(cs ^ (r0 & 7)) * 8];
        s16x8 k1 = *(const s16x8*)&Ks[cur][r1][(cs ^ (r1 & 7)) * 8];
        S0 = mfma32(k0, qf[c], S0);
        S1 = mfma32(k1, qf[c], S1);
      }
      if (kb + 63 > qminw) {
#pragma unroll
        for (int r = 0; r < 16; r++) {
          int key0 = kb + (r & 3) + 8 * (r >> 2) + 4 * hi;
          S0[r] = (key0 <= qrow) ? S0[r] : -1e30f;
          S1[r] = (key0 + 32 <= qrow) ? S1[r] : -1e30f;
        }
      }
      float t8[8];
#pragma unroll
      for (int r = 0; r < 8; r++)
        t8[r] = fmaxf(fmaxf(S0[2 * r], S0[2 * r + 1]),
                      fmaxf(S1[2 * r], S1[2 * r + 1]));
      float tmax = fmaxf(fmaxf(fmaxf(t8[0], t8[1]), fmaxf(t8[2], t8[3])),
                         fmaxf(fmaxf(t8[4], t8[5]), fmaxf(t8[6], t8[7])));
      tmax = fmaxf(tmax, __shfl_xor(tmax, 32));
      if (!__all(tmax <= m + 11.0f)) {
        float mn = fmaxf(m, tmax);
        float alpha = __builtin_amdgcn_exp2f(m - mn);
        ll *= alpha;
#pragma unroll
        for (int r = 0; r < 16; r++) {
          acc0[r] *= alpha;
          acc1[r] *= alpha;
        }
        m = mn;
      }
#pragma unroll
      for (int r = 0; r < 16; r++) {
        S0[r] = __builtin_amdgcn_exp2f(S0[r] - m);
        S1[r] = __builtin_amdgcn_exp2f(S1[r] - m);
      }
      float s8[8];
#pragma unroll
      for (int r = 0; r < 8; r++)
        s8[r] = (S0[2 * r] + S0[2 * r + 1]) + (S1[2 * r] + S1[2 * r + 1]);
      float rs = ((s8[0] + s8[1]) + (s8[2] + s8[3])) +
                 ((s8[4] + s8[5]) + (s8[6] + s8[7]));
      rs += __shfl_xor(rs, 32);
      ll += rs;
#pragma unroll
      for (int half = 0; half < 2; half++) {
        const f32x16& S = half ? S1 : S0;
        u32x4 pbAv, pbBv;
#pragma unroll
        for (int g = 0; g < 4; g++) {
          unsigned int lo = (unsigned short)f2bf(S[2 * g]);
          unsigned int h16 = (unsigned short)f2bf(S[2 * g + 1]);
          pbAv[g] = lo | (h16 << 16);
          unsigned int lo2 = (unsigned short)f2bf(S[8 + 2 * g]);
          unsigned int h162 = (unsigned short)f2bf(S[9 + 2 * g]);
          pbBv[g] = lo2 | (h162 << 16);
        }
#pragma unroll
        for (int gg = 0; gg < 2; gg++) {
          s16x8 pb = __builtin_bit_cast(s16x8, gg ? pbBv : pbAv);
          int cs = (half * 2 + gg) * 2 + hi;
          int v0r = l32;
          int v1r = 32 + l32;
          s16x8 va0 = *(const s16x8*)&Vs[cur][v0r][(cs ^ (v0r & 7)) * 8];
          s16x8 va1 = *(const s16x8*)&Vs[cur][v1r][(cs ^ (v1r & 7)) * 8];
          acc0 = mfma32(va0, pb, acc0);
          acc1 = mfma32(va1, pb, acc1);
        }
      }
    }
    if (kt + 1 < nt) WRITET(cur ^ 1);
    __syncthreads();
    cur ^= 1;
  }

  float inv = 1.f / ll;
  size_t rowbase = ((size_t)(b * S_LEN + qrow)) * DMODEL + h * HDIM;
#pragma unroll
  for (int g = 0; g < 4; g++) {
    s16x4 o0, o1;
#pragma unroll
    for (int u = 0; u < 4; u++) {
      o0[u] = f2bf(acc0[4 * g + u] * inv);
      o1[u] = f2bf(acc1[4 * g + u] * inv);
    }
    *(s16x4*)&AO[rowbase + 8 * g + 4 * hi] = o0;
    *(s16x4*)&AO[rowbase + 32 + 8 * g + 4 * hi] = o1;
  }
}

// ---- fallback (ws too small): k-split kernel, f32 K ----
__global__ __launch_bounds__(256, 4) void attn_fwd_kf32(
    const short* __restrict__ Q, const float* __restrict__ Kraw,
    const short* __restrict__ Vt, short* __restrict__ AO) {
  __shared__ float XFER[2][64][37];
  const int p = blockIdx.x;
  const int xcd = p & 7;
  const int rank = p >> 3;
  const int bh = (xcd << 2) | (rank >> 5);
  const int pr = rank & 31;
  const int tid = threadIdx.x;
  const int w = tid >> 6;
  const int lane = tid & 63;
  const int l32 = lane & 31;
  const int hi = lane >> 5;
  const short* Qb = Q + (size_t)bh * (S_LEN * HDIM);
  const short* Vb = Vt + (size_t)bh * (HDIM * S_LEN);
  const float* Kb32 = Kraw + (size_t)bh * (S_LEN * HDIM);
  const int b = bh >> 4, h = bh & 15;

#pragma unroll 1
  for (int ph = 0; ph < 2; ph++) {
    const int j = ph ? pr : 63 - pr;
    const int qb = j * 32;
    s16x8 qf[4];
#pragma unroll
    for (int c = 0; c < 4; c++)
      qf[c] = *(const s16x8*)&Qb[(size_t)(qb + l32) * HDIM + c * 16 + hi * 8];
    f32x16 acc0 = {0.f}, acc1 = {0.f};
    float m = -1e30f, ll = 0.f;
#pragma unroll 1
    for (int kt = w; kt <= j; kt += 4) {
      const int kb = kt * 32;
      f32x16 S = {0.f};
#pragma unroll
      for (int c = 0; c < 4; c++) {
        const float* kr = &Kb32[(size_t)(kb + l32) * HDIM + c * 16 + hi * 8];
        f32x4 k0 = *(const f32x4*)kr, k1 = *(const f32x4*)(kr + 4);
        s16x8 kf;
#pragma unroll
        for (int u = 0; u < 4; u++) {
          kf[u] = f2bf(k0[u]);
          kf[4 + u] = f2bf(k1[u]);
        }
        S = mfma32(kf, qf[c], S);
      }
      const short* vr0 = &Vb[(size_t)l32 * S_LEN + kb + hi * 8];
      const short* vr1 = &Vb[(size_t)(32 + l32) * S_LEN + kb + hi * 8];
      s16x8 va00 = *(const s16x8*)vr0;
      s16x8 va01 = *(const s16x8*)(vr0 + 16);
      s16x8 va10 = *(const s16x8*)vr1;
      s16x8 va11 = *(const s16x8*)(vr1 + 16);
      if (kt == j) {
#pragma unroll
        for (int r = 0; r < 16; r++) {
          int keyl = (r & 3) + 8 * (r >> 2) + 4 * hi;
          S[r] = (keyl <= l32) ? S[r] : -1e30f;
        }
      }
      float t8[8];
#pragma unroll
      for (int r = 0; r < 8; r++) t8[r] = fmaxf(S[2 * r], S[2 * r + 1]);
      float tmax = fmaxf(fmaxf(fmaxf(t8[0], t8[1]), fmaxf(t8[2], t8[3])),
                         fmaxf(fmaxf(t8[4], t8[5]), fmaxf(t8[6], t8[7])));
      tmax = fmaxf(tmax, __shfl_xor(tmax, 32));
      if (!__all(tmax <= m + 11.0f)) {
        float mn = fmaxf(m, tmax);
        float alpha = __builtin_amdgcn_exp2f(m - mn);
        ll *= alpha;
#pragma unroll
        for (int r = 0; r < 16; r++) {
          acc0[r] *= alpha;
          acc1[r] *= alpha;
        }
        m = mn;
      }
#pragma unroll
      for (int r = 0; r < 16; r++) S[r] = __builtin_amdgcn_exp2f(S[r] - m);
      float s8[8];
#pragma unroll
      for (int r = 0; r < 8; r++) s8[r] = S[2 * r] + S[2 * r + 1];
      float rs = ((s8[0] + s8[1]) + (s8[2] + s8[3])) +
                 ((s8[4] + s8[5]) + (s8[6] + s8[7]));
      rs += __shfl_xor(rs, 32);
      ll += rs;
      u32x4 pb0v, pb1v;
#pragma unroll
      for (int g = 0; g < 4; g++) {
        unsigned int lo = (unsigned short)f2bf(S[2 * g]);
        unsigned int h16 = (unsigned short)f2bf(S[2 * g + 1]);
        pb0v[g] = lo | (h16 << 16);
        unsigned int lo2 = (unsigned short)f2bf(S[8 + 2 * g]);
        unsigned int h162 = (unsigned short)f2bf(S[9 + 2 * g]);
        pb1v[g] = lo2 | (h162 << 16);
      }
      s16x8 pb0 = __builtin_bit_cast(s16x8, pb0v);
      s16x8 pb1 = __builtin_bit_cast(s16x8, pb1v);
      acc0 = mfma32(va00, pb0, acc0);
      acc1 = mfma32(va10, pb0, acc1);
      acc0 = mfma32(va01, pb1, acc0);
      acc1 = mfma32(va11, pb1, acc1);
    }
    if (w & 1) {
      float* dst = &XFER[w >> 1][lane][0];
      dst[0] = m; dst[1] = ll;
#pragma unroll
      for (int r = 0; r < 16; r++) { dst[2 + r] = acc0[r]; dst[18 + r] = acc1[r]; }
    }
    __syncthreads();
    if (!(w & 1)) {
      const float* src = &XFER[w >> 1][lane][0];
      float m2 = src[0], l2 = src[1];
      float M = fmaxf(m, m2);
      float a1 = __builtin_amdgcn_exp2f(m - M);
      float a2 = __builtin_amdgcn_exp2f(m2 - M);
      ll = ll * a1 + l2 * a2;
#pragma unroll
      for (int r = 0; r < 16; r++) {
        acc0[r] = acc0[r] * a1 + src[2 + r] * a2;
        acc1[r] = acc1[r] * a1 + src[18 + r] * a2;
      }
      m = M;
    }
    __syncthreads();
    if (w == 2) {
      float* dst = &XFER[0][lane][0];
      dst[0] = m; dst[1] = ll;
#pragma unroll
      for (int r = 0; r < 16; r++) { dst[2 + r] = acc0[r]; dst[18 + r] = acc1[r]; }
    }
    __syncthreads();
    if (w == 0) {
      const float* src = &XFER[0][lane][0];
      float m2 = src[0], l2 = src[1];
      float M = fmaxf(m, m2);
      float a1 = __builtin_amdgcn_exp2f(m - M);
      float a2 = __builtin_amdgcn_exp2f(m2 - M);
      ll = ll * a1 + l2 * a2;
#pragma unroll
      for (int r = 0; r < 16; r++) {
        acc0[r] = acc0[r] * a1 + src[2 + r] * a2;
        acc1[r] = acc1[r] * a1 + src[18 + r] * a2;
      }
      float inv = 1.f / ll;
      size_t rowbase = ((size_t)(b * S_LEN + qb + l32)) * DMODEL + h * HDIM;
#pragma unroll
      for (int g = 0; g < 4; g++) {
        s16x4 o0, o1;
#pragma unroll
        for (int u = 0; u < 4; u++) {
          o0[u] = f2bf(acc0[4 * g + u] * inv);
          o1[u] = f2bf(acc1[4 * g + u] * inv);
        }
        *(s16x4*)&AO[rowbase + 8 * g + 4 * hi] = o0;
        *(s16x4*)&AO[rowbase + 32 + 8 * g + 4 * hi] = o1;
      }
    }
    __syncthreads();
  }
}

extern "C" void kernel_launch(void* const* d_in, const int* in_sizes, int n_in,
                              void* d_out, int out_size, void* d_ws,
                              size_t ws_size, hipStream_t stream) {
  const float* x = (const float*)d_in[0];
  const float* w_qkv = (const float*)d_in[1];
  const float* b_qkv = (const float*)d_in[2];
  const float* w_proj = (const float*)d_in[3];
  const float* b_proj = (const float*)d_in[4];
  float* out = (float*)d_out;
  float* presentK = out + OUT_ELEMS;            // f32 [bh][S][64]
  float* presentV = presentK + HEAD_ELEMS;      // f32 [bh][S][64]

  // bf16 copy of x lives in the (dead until proj) `out` region
  short* xbf = (short*)out;

  short* ws = (short*)d_ws;
  const bool kbf16 = ws_size >= (size_t)35651584;

  short *Qw, *Vt, *wprojT, *wqkvT, *attnout, *Kw;
  if (kbf16) {
    Qw = ws;                  // 4,194,304
    Kw = ws + 4194304;        // 4,194,304
    Vt = ws + 8388608;        // 4,194,304
    wprojT = ws + 12582912;   // 1,048,576
    wqkvT = ws + 13631488;    // 3,145,728 (dead after QKV gemm)
    attnout = ws + 13631488;  // 4,194,304 (overlays wqkvT)
  } else {
    if (ws_size < (size_t)27262976) return;
    Qw = ws;
    Vt = ws + 4194304;
    wprojT = ws + 8388608;
    wqkvT = ws + 9437184;
    attnout = ws + 9437184;
    Kw = nullptr;
  }

  cvt_bf16<<<dim3(2048), 256, 0, stream>>>(x, xbf);
  transpose_cvt<<<dim3(1536), 256, 0, stream>>>(w_qkv, wqkvT, 1024, 3072);
  transpose_cvt<<<dim3(512), 256, 0, stream>>>(w_proj, wprojT, 1024, 1024);
  // QKV projection: Q(pre-scaled)->Qw, K->presentK f32 + Kw bf16, V->f32
  gemm_bt<0><<<dim3(24, 32), 256, 0, stream>>>(
      xbf, wqkvT, b_qkv, Qw, presentK, kbf16 ? Kw : Qw /*unused-safe*/, 4096,
      3072, 1024);
  // sigma-permuted V^T from presentV (coalesced LDS transpose)
  vtrans<<<dim3(1024), 256, 0, stream>>>(presentV, Vt);
  // causal attention
  if (kbf16)
    attn_fwd_kbf16<<<dim3(512), 256, 0, stream>>>(Qw, Kw, Vt, attnout);
  else
    attn_fwd_kf32<<<dim3(1024), 256, 0, stream>>>(Qw, presentK, Vt, attnout);
  // output projection -> f32 out (xbf region dead by now)
  gemm_bt<1><<<dim3(8, 32), 256, 0, stream>>>(
      attnout, wprojT, b_proj, nullptr, out, nullptr, 4096, 1024, 1024);
}

// Round 12
// 119.625 us; speedup vs baseline: 1.0958x; 1.0653x over previous
//
#include <hip/hip_runtime.h>
#include <hip/hip_bf16.h>

typedef short s16x8 __attribute__((ext_vector_type(8)));
typedef short s16x4 __attribute__((ext_vector_type(4)));
typedef float f32x4 __attribute__((ext_vector_type(4)));
typedef float f32x16 __attribute__((ext_vector_type(16)));
typedef unsigned int u32x4 __attribute__((ext_vector_type(4)));

#define S_LEN 2048
#define DMODEL 1024
#define NHEAD 16
#define HDIM 64
#define OUT_ELEMS 4194304   // B*S*D
#define HEAD_ELEMS 4194304  // B*H*S*HD
#define SCALE_LOG2 0.1803368801111204f  // 0.125 * log2(e), folded into Q

__device__ inline short f2bf(float f) {
  __hip_bfloat16 h = __float2bfloat16(f);  // RNE
  return __builtin_bit_cast(short, h);
}

__device__ inline f32x4 mfma16(s16x8 a, s16x8 b, f32x4 c) {
  return __builtin_amdgcn_mfma_f32_16x16x32_bf16(a, b, c, 0, 0, 0);
}
__device__ inline f32x16 mfma32(s16x8 a, s16x8 b, f32x16 c) {
  return __builtin_amdgcn_mfma_f32_32x32x16_bf16(a, b, c, 0, 0, 0);
}

typedef __attribute__((address_space(1))) const void gvoid;
typedef __attribute__((address_space(3))) void lvoid;
__device__ inline void gload_lds16(const void* g, void* l) {
  __builtin_amdgcn_global_load_lds((gvoid*)g, (lvoid*)l, 16, 0, 0);
}

// ---- elementwise f32 -> bf16 (8 elems/thread) ----
__global__ __launch_bounds__(256) void cvt_bf16(const float* __restrict__ in,
                                                short* __restrict__ out) {
  int g = blockIdx.x * 256 + threadIdx.x;
  const float* p = &in[(size_t)g * 8];
  f32x4 a = *(const f32x4*)p;
  f32x4 b = *(const f32x4*)(p + 4);
  s16x8 v;
#pragma unroll
  for (int j = 0; j < 4; j++) {
    v[j] = f2bf(a[j]);
    v[4 + j] = f2bf(b[j]);
  }
  *(s16x8*)&out[(size_t)g * 8] = v;
}

// ---- convert+transpose: in [R][C] f32 -> out [C][R] bf16 (weights) ----
__global__ __launch_bounds__(256) void transpose_cvt(
    const float* __restrict__ in, short* __restrict__ out, int R, int C) {
  int g = blockIdx.x * 256 + threadIdx.x;
  int c = g % C;
  int r0 = (g / C) * 8;
  s16x8 v;
#pragma unroll
  for (int j = 0; j < 8; j++) v[j] = f2bf(in[(size_t)(r0 + j) * C + c]);
  *(s16x8*)&out[(size_t)c * R + r0] = v;
}

// ---- K f32 [bh][S][64] -> Kf fragment-linear bf16 -----------------------
// Kf[((bh*64+kt)*4+c)*512 + lane*8 + u] = K[bh][kt*32+(lane&31)][c*16+(lane>>5)*8+u]
__global__ __launch_bounds__(256) void kfrag(const float* __restrict__ Kp,
                                             short* __restrict__ Kf) {
  __shared__ short Kl[128][66];
  const int p = blockIdx.x;  // 512 = 32 bh x 16 blk4
  const int bh = p & 31;
  const int blk4 = p >> 5;   // 4 key-tiles (128 keys)
  const float* src = Kp + ((size_t)bh * S_LEN + (size_t)blk4 * 128) * HDIM;
  const int t = threadIdx.x;
#pragma unroll
  for (int rep = 0; rep < 8; rep++) {
    int idx = rep * 256 + t;
    int row = idx >> 4, ch = idx & 15;  // 16B f32 chunk
    f32x4 a = *(const f32x4*)&src[row * 64 + ch * 4];
    s16x4 v;
#pragma unroll
    for (int j = 0; j < 4; j++) v[j] = f2bf(a[j]);
    *(s16x4*)&Kl[row][ch * 4] = v;
  }
  __syncthreads();
  const int c = t >> 6, lane = t & 63;
  const int l32 = lane & 31, hi = lane >> 5;
  short* dst = Kf + (((size_t)bh * 64 + blk4 * 4) * 4 + c) * 512 + lane * 8;
#pragma unroll
  for (int q = 0; q < 4; q++) {
    s16x8 v = *(const s16x8*)&Kl[q * 32 + l32][c * 16 + hi * 8];
    *(s16x8*)&dst[(size_t)q * 4 * 512] = v;
  }
}

// ---- V f32 [bh][S][64] -> Vf fragment-linear bf16 (sigma perm baked) ----
// Vf[((bh*64+kt)*4 + kc*2 + f)*512 + lane*8 + u]
//   = V[bh][kt*32 + sigma(kc*16+hi*8+u)][f*32 + l32]
// sigma swaps bits 2,3: rows = kc*16 + (hi?4:0) + {u, 8+u-4...}
__global__ __launch_bounds__(256) void vfrag(const float* __restrict__ Vp,
                                             short* __restrict__ Vf) {
  __shared__ short Vl[64][66];
  const int p = blockIdx.x;  // 1024 = 32 bh x 32 kt64
  const int bh = p & 31;
  const int kt64 = p >> 5;   // 2 key-tiles (64 keys)
  const float* src = Vp + ((size_t)bh * S_LEN + (size_t)kt64 * 64) * HDIM;
  const int t = threadIdx.x;
#pragma unroll
  for (int rep = 0; rep < 4; rep++) {
    int idx = rep * 256 + t;
    int row = idx >> 4, ch = idx & 15;
    f32x4 a = *(const f32x4*)&src[row * 64 + ch * 4];
    s16x4 v;
#pragma unroll
    for (int j = 0; j < 4; j++) v[j] = f2bf(a[j]);
    *(s16x4*)&Vl[row][ch * 4] = v;
  }
  __syncthreads();
  const int stkc = t >> 6, lane = t & 63;
  const int st = stkc >> 1, kc = stkc & 1;
  const int l32 = lane & 31, hi = lane >> 5;
  const int rowbase = st * 32 + kc * 16 + (hi ? 4 : 0);
#pragma unroll
  for (int f = 0; f < 2; f++) {
    int col = f * 32 + l32;
    s16x8 v;
#pragma unroll
    for (int u = 0; u < 4; u++) {
      v[u] = Vl[rowbase + u][col];
      v[4 + u] = Vl[rowbase + 8 + u][col];
    }
    size_t o = (((size_t)bh * 64 + kt64 * 2 + st) * 4 + kc * 2 + f) * 512 +
               lane * 8;
    *(s16x8*)&Vf[o] = v;
  }
}

// ---- GEMM: C = A[M,K] * Bt[N,K]^T + bias. bf16, gload_lds, BK=64, swizzle.
template <int MODE>
__global__ __launch_bounds__(256) void gemm_bt(
    const short* __restrict__ A, const short* __restrict__ Bt,
    const float* __restrict__ bias, short* __restrict__ Ob0,
    float* __restrict__ Of, int M, int N, int K) {
  __shared__ short As[128 * 64];
  __shared__ short Bs[128 * 64];
  const int t = threadIdx.x;
  const int lane = t & 63;
  const int wid = t >> 6;
  const int wr = wid >> 1, wc = wid & 1;
  const int l16 = lane & 15, lg = lane >> 4;
  const int mbase = blockIdx.y * 128;
  const int nbase = blockIdx.x * 128;

  f32x4 acc[4][4];
#pragma unroll
  for (int m = 0; m < 4; m++)
#pragma unroll
    for (int n = 0; n < 4; n++) acc[m][n] = (f32x4){0.f, 0.f, 0.f, 0.f};

  const int srow = lane >> 3;
  const int sgr = (lane & 7) ^ srow;
  const short* Ag = &A[(size_t)(mbase + wid * 32 + srow) * K + sgr * 8];
  const short* Bg = &Bt[(size_t)(nbase + wid * 32 + srow) * K + sgr * 8];

  for (int k0 = 0; k0 < K; k0 += 64) {
    __syncthreads();
#pragma unroll
    for (int c = 0; c < 4; c++)
      gload_lds16(Ag + (size_t)(c * 8) * K + k0, &As[(wid * 32 + c * 8) * 64]);
#pragma unroll
    for (int c = 0; c < 4; c++)
      gload_lds16(Bg + (size_t)(c * 8) * K + k0, &Bs[(wid * 32 + c * 8) * 64]);
    __syncthreads();
    s16x8 af[4][2], bfr[4][2];
#pragma unroll
    for (int m = 0; m < 4; m++) {
      int row = wr * 64 + m * 16 + l16;
#pragma unroll
      for (int h = 0; h < 2; h++) {
        int gr = (h * 4 + lg) ^ (row & 7);
        af[m][h] = *(const s16x8*)&As[row * 64 + gr * 8];
      }
    }
#pragma unroll
    for (int n = 0; n < 4; n++) {
      int row = wc * 64 + n * 16 + l16;
#pragma unroll
      for (int h = 0; h < 2; h++) {
        int gr = (h * 4 + lg) ^ (row & 7);
        bfr[n][h] = *(const s16x8*)&Bs[row * 64 + gr * 8];
      }
    }
#pragma unroll
    for (int m = 0; m < 4; m++)
#pragma unroll
      for (int n = 0; n < 4; n++) {
        acc[m][n] = mfma16(af[m][0], bfr[n][0], acc[m][n]);
        acc[m][n] = mfma16(af[m][1], bfr[n][1], acc[m][n]);
      }
  }

#pragma unroll
  for (int m = 0; m < 4; m++) {
#pragma unroll
    for (int n = 0; n < 4; n++) {
      int gcol = nbase + wc * 64 + n * 16 + l16;
      float bv = bias[gcol];
      int part = gcol >> 10;
      int cin = gcol & 1023;
      int h = cin >> 6, hd = cin & 63;
      int grow0 = mbase + wr * 64 + m * 16 + lg * 4;
      float vr[4];
#pragma unroll
      for (int r = 0; r < 4; r++) vr[r] = acc[m][n][r] + bv;
      if (MODE == 0) {
        int bb = grow0 >> 11, s0 = grow0 & 2047;
        size_t base = ((size_t)(bb * NHEAD + h) * S_LEN + s0) * HDIM + hd;
        if (part == 0) {
#pragma unroll
          for (int r = 0; r < 4; r++)
            Ob0[base + (size_t)r * HDIM] = f2bf(vr[r] * SCALE_LOG2);
        } else if (part == 1) {
#pragma unroll
          for (int r = 0; r < 4; r++) Of[base + (size_t)r * HDIM] = vr[r];
        } else {
#pragma unroll
          for (int r = 0; r < 4; r++)
            Of[HEAD_ELEMS + base + (size_t)r * HDIM] = vr[r];
        }
      } else {
#pragma unroll
        for (int r = 0; r < 4; r++) Of[(size_t)(grow0 + r) * N + gcol] = vr[r];
      }
    }
  }
}

// ==== attention: round-8 structure + fragment-linear K/V (coalesced) ====
// paired q-tiles (j, 63-j) per block, k-split across 4 waves + LDS combine
template <bool KFRAG>
__device__ __forceinline__ void attn_body(const short* __restrict__ Q,
                                          const void* __restrict__ Kraw,
                                          const short* __restrict__ Vf,
                                          short* __restrict__ AO) {
  __shared__ float XFER[2][64][37];

  const int p = blockIdx.x;                 // 1024 blocks
  const int xcd = p & 7;
  const int rank = p >> 3;
  const int bh = (xcd << 2) | (rank >> 5);
  const int pr = rank & 31;

  const int tid = threadIdx.x;
  const int w = tid >> 6;
  const int lane = tid & 63;
  const int l32 = lane & 31;
  const int hi = lane >> 5;

  const short* Qb = Q + (size_t)bh * (S_LEN * HDIM);
  const short* Kfb = (const short*)Kraw + (size_t)bh * (64 * 2048);
  const float* Kb32 = (const float*)Kraw + (size_t)bh * (S_LEN * HDIM);
  const short* Vfb = Vf + (size_t)bh * (64 * 2048);
  const int b = bh >> 4, h = bh & 15;

#pragma unroll 1
  for (int ph = 0; ph < 2; ph++) {
    const int j = ph ? pr : 63 - pr;
    const int qb = j * 32;

    s16x8 qf[4];
#pragma unroll
    for (int c = 0; c < 4; c++)
      qf[c] = *(const s16x8*)&Qb[(size_t)(qb + l32) * HDIM + c * 16 + hi * 8];

    f32x16 acc0 = {0.f}, acc1 = {0.f};
    float m = -1e30f, ll = 0.f;

    s16x8 kcur[4];
    if constexpr (KFRAG) {
      if (w <= j) {
#pragma unroll
        for (int c = 0; c < 4; c++)
          kcur[c] =
              *(const s16x8*)&Kfb[(size_t)w * 2048 + c * 512 + lane * 8];
      }
    }

#pragma unroll 1
    for (int kt = w; kt <= j; kt += 4) {
      // S^T[key][q] = K . Q^T
      f32x16 S = {0.f};
      if constexpr (KFRAG) {
#pragma unroll
        for (int c = 0; c < 4; c++) S = mfma32(kcur[c], qf[c], S);
      } else {
        const int kb = kt * 32;
#pragma unroll
        for (int c = 0; c < 4; c++) {
          const float* kr = &Kb32[(size_t)(kb + l32) * HDIM + c * 16 + hi * 8];
          f32x4 k0 = *(const f32x4*)kr, k1 = *(const f32x4*)(kr + 4);
          s16x8 kf;
#pragma unroll
          for (int u = 0; u < 4; u++) {
            kf[u] = f2bf(k0[u]);
            kf[4 + u] = f2bf(k1[u]);
          }
          S = mfma32(kf, qf[c], S);
        }
      }
      // V fragment loads: fully coalesced (lane*16B)
      const short* vb = &Vfb[(size_t)kt * 2048 + lane * 8];
      s16x8 va00 = *(const s16x8*)vb;            // kc0, f0 (dims l32)
      s16x8 va10 = *(const s16x8*)(vb + 512);    // kc0, f1 (dims 32+l32)
      s16x8 va01 = *(const s16x8*)(vb + 1024);   // kc1, f0
      s16x8 va11 = *(const s16x8*)(vb + 1536);   // kc1, f1
      // prefetch next K fragment tile
      if constexpr (KFRAG) {
        if (kt + 4 <= j) {
#pragma unroll
          for (int c = 0; c < 4; c++)
            kcur[c] = *(const s16x8*)&Kfb[(size_t)(kt + 4) * 2048 + c * 512 +
                                          lane * 8];
        }
      }
      // causal mask on diagonal tile
      if (kt == j) {
#pragma unroll
        for (int r = 0; r < 16; r++) {
          int keyl = (r & 3) + 8 * (r >> 2) + 4 * hi;
          S[r] = (keyl <= l32) ? S[r] : -1e30f;
        }
      }
      // tile max
      float t8[8];
#pragma unroll
      for (int r = 0; r < 8; r++) t8[r] = fmaxf(S[2 * r], S[2 * r + 1]);
      float tmax = fmaxf(fmaxf(fmaxf(t8[0], t8[1]), fmaxf(t8[2], t8[3])),
                         fmaxf(fmaxf(t8[4], t8[5]), fmaxf(t8[6], t8[7])));
      tmax = fmaxf(tmax, __shfl_xor(tmax, 32));
      // defer-max rescale
      if (!__all(tmax <= m + 11.0f)) {
        float mn = fmaxf(m, tmax);
        float alpha = __builtin_amdgcn_exp2f(m - mn);
        ll *= alpha;
#pragma unroll
        for (int r = 0; r < 16; r++) {
          acc0[r] *= alpha;
          acc1[r] *= alpha;
        }
        m = mn;
      }
#pragma unroll
      for (int r = 0; r < 16; r++) S[r] = __builtin_amdgcn_exp2f(S[r] - m);
      // tile sum
      float s8[8];
#pragma unroll
      for (int r = 0; r < 8; r++) s8[r] = S[2 * r] + S[2 * r + 1];
      float rs = ((s8[0] + s8[1]) + (s8[2] + s8[3])) +
                 ((s8[4] + s8[5]) + (s8[6] + s8[7]));
      rs += __shfl_xor(rs, 32);
      ll += rs;
      // pack P (scalar casts; compiler fuses)
      u32x4 pb0v, pb1v;
#pragma unroll
      for (int g = 0; g < 4; g++) {
        unsigned int lo = (unsigned short)f2bf(S[2 * g]);
        unsigned int h16 = (unsigned short)f2bf(S[2 * g + 1]);
        pb0v[g] = lo | (h16 << 16);
        unsigned int lo2 = (unsigned short)f2bf(S[8 + 2 * g]);
        unsigned int h162 = (unsigned short)f2bf(S[9 + 2 * g]);
        pb1v[g] = lo2 | (h162 << 16);
      }
      s16x8 pb0 = __builtin_bit_cast(s16x8, pb0v);
      s16x8 pb1 = __builtin_bit_cast(s16x8, pb1v);
      acc0 = mfma32(va00, pb0, acc0);
      acc1 = mfma32(va10, pb0, acc1);
      acc0 = mfma32(va01, pb1, acc0);
      acc1 = mfma32(va11, pb1, acc1);
    }

    // ---- combine the 4 per-wave partials (tree merge via LDS) ----
    if (w & 1) {
      float* dst = &XFER[w >> 1][lane][0];
      dst[0] = m; dst[1] = ll;
#pragma unroll
      for (int r = 0; r < 16; r++) { dst[2 + r] = acc0[r]; dst[18 + r] = acc1[r]; }
    }
    __syncthreads();
    if (!(w & 1)) {
      const float* src = &XFER[w >> 1][lane][0];
      float m2 = src[0], l2 = src[1];
      float M = fmaxf(m, m2);
      float a1 = __builtin_amdgcn_exp2f(m - M);
      float a2 = __builtin_amdgcn_exp2f(m2 - M);
      ll = ll * a1 + l2 * a2;
#pragma unroll
      for (int r = 0; r < 16; r++) {
        acc0[r] = acc0[r] * a1 + src[2 + r] * a2;
        acc1[r] = acc1[r] * a1 + src[18 + r] * a2;
      }
      m = M;
    }
    __syncthreads();
    if (w == 2) {
      float* dst = &XFER[0][lane][0];
      dst[0] = m; dst[1] = ll;
#pragma unroll
      for (int r = 0; r < 16; r++) { dst[2 + r] = acc0[r]; dst[18 + r] = acc1[r]; }
    }
    __syncthreads();
    if (w == 0) {
      const float* src = &XFER[0][lane][0];
      float m2 = src[0], l2 = src[1];
      float M = fmaxf(m, m2);
      float a1 = __builtin_amdgcn_exp2f(m - M);
      float a2 = __builtin_amdgcn_exp2f(m2 - M);
      ll = ll * a1 + l2 * a2;
#pragma unroll
      for (int r = 0; r < 16; r++) {
        acc0[r] = acc0[r] * a1 + src[2 + r] * a2;
        acc1[r] = acc1[r] * a1 + src[18 + r] * a2;
      }
      float inv = 1.f / ll;
      size_t rowbase = ((size_t)(b * S_LEN + qb + l32)) * DMODEL + h * HDIM;
#pragma unroll
      for (int g = 0; g < 4; g++) {
        s16x4 o0, o1;
#pragma unroll
        for (int u = 0; u < 4; u++) {
          o0[u] = f2bf(acc0[4 * g + u] * inv);
          o1[u] = f2bf(acc1[4 * g + u] * inv);
        }
        *(s16x4*)&AO[rowbase + 8 * g + 4 * hi] = o0;
        *(s16x4*)&AO[rowbase + 32 + 8 * g + 4 * hi] = o1;
      }
    }
    __syncthreads();
  }
}

__global__ __launch_bounds__(256, 4) void attn_fwd_frag(
    const short* __restrict__ Q, const short* __restrict__ Kf,
    const short* __restrict__ Vf, short* __restrict__ AO) {
  attn_body<true>(Q, Kf, Vf, AO);
}
__global__ __launch_bounds__(256, 4) void attn_fwd_kf32(
    const short* __restrict__ Q, const float* __restrict__ K,
    const short* __restrict__ Vf, short* __restrict__ AO) {
  attn_body<false>(Q, K, Vf, AO);
}

extern "C" void kernel_launch(void* const* d_in, const int* in_sizes, int n_in,
                              void* d_out, int out_size, void* d_ws,
                              size_t ws_size, hipStream_t stream) {
  const float* x = (const float*)d_in[0];
  const float* w_qkv = (const float*)d_in[1];
  const float* b_qkv = (const float*)d_in[2];
  const float* w_proj = (const float*)d_in[3];
  const float* b_proj = (const float*)d_in[4];
  float* out = (float*)d_out;
  float* presentK = out + OUT_ELEMS;            // f32 [bh][S][64]
  float* presentV = presentK + HEAD_ELEMS;      // f32 [bh][S][64]

  short* xbf = (short*)out;  // dead-until-proj region

  short* ws = (short*)d_ws;
  const bool kbf16 = ws_size >= (size_t)35651584;

  short *Qw, *Vf, *wprojT, *wqkvT, *attnout, *Kf;
  if (kbf16) {
    Qw = ws;                  // 4,194,304
    Kf = ws + 4194304;        // 4,194,304 (fragment-linear K)
    Vf = ws + 8388608;        // 4,194,304 (fragment-linear V)
    wprojT = ws + 12582912;   // 1,048,576
    wqkvT = ws + 13631488;    // 3,145,728 (dead after QKV gemm)
    attnout = ws + 13631488;  // 4,194,304 (overlays wqkvT)
  } else {
    if (ws_size < (size_t)27262976) return;
    Qw = ws;
    Vf = ws + 4194304;
    wprojT = ws + 8388608;
    wqkvT = ws + 9437184;
    attnout = ws + 9437184;
    Kf = nullptr;
  }

  cvt_bf16<<<dim3(2048), 256, 0, stream>>>(x, xbf);
  transpose_cvt<<<dim3(1536), 256, 0, stream>>>(w_qkv, wqkvT, 1024, 3072);
  transpose_cvt<<<dim3(512), 256, 0, stream>>>(w_proj, wprojT, 1024, 1024);
  // QKV projection: Q(pre-scaled)->Qw bf16, K/V->present f32
  gemm_bt<0><<<dim3(24, 32), 256, 0, stream>>>(xbf, wqkvT, b_qkv, Qw,
                                               presentK, 4096, 3072, 1024);
  // fragment-linear repacks (coalesced both sides)
  if (kbf16) kfrag<<<dim3(512), 256, 0, stream>>>(presentK, Kf);
  vfrag<<<dim3(1024), 256, 0, stream>>>(presentV, Vf);
  // causal attention
  if (kbf16)
    attn_fwd_frag<<<dim3(1024), 256, 0, stream>>>(Qw, Kf, Vf, attnout);
  else
    attn_fwd_kf32<<<dim3(1024), 256, 0, stream>>>(Qw, presentK, Vf, attnout);
  // output projection -> f32 out (xbf dead by now)
  gemm_bt<1><<<dim3(8, 32), 256, 0, stream>>>(attnout, wprojT, b_proj,
                                              nullptr, out, 4096, 1024, 1024);
}